// Round 1
// baseline (1047.264 us; speedup 1.0000x reference)
//
#include <hip/hip_runtime.h>
#include <math.h>

// Problem constants (from reference)
#define N_    128
#define T_    1000
#define NS_   10
#define NO_   10
#define HID_  64
#define G3_   192   // 3*HID
#define DENSE_ 32

// ---------------------------------------------------------------------------
// Phase 0: precompute Cinv = inv(C_w), A = H^T Cinv (NS x NO), M = A H (NS x NS)
// Single-thread Gauss-Jordan on a 10x10 (runs once per launch, trivial cost).
// ---------------------------------------------------------------------------
__global__ void setup_consts(const float* __restrict__ H,
                             const float* __restrict__ C_w,
                             float* __restrict__ A,   // (NS,NO)
                             float* __restrict__ M)   // (NS,NS)
{
    if (threadIdx.x != 0 || blockIdx.x != 0) return;
    float W[NO_][2 * NO_];
    for (int i = 0; i < NO_; ++i) {
        for (int j = 0; j < NO_; ++j) {
            W[i][j] = C_w[i * NO_ + j];
            W[i][NO_ + j] = (i == j) ? 1.f : 0.f;
        }
    }
    // SPD, no pivoting needed
    for (int p = 0; p < NO_; ++p) {
        float ip = 1.f / W[p][p];
        for (int j = 0; j < 2 * NO_; ++j) W[p][j] *= ip;
        for (int i = 0; i < NO_; ++i) {
            if (i == p) continue;
            float f = W[i][p];
            for (int j = 0; j < 2 * NO_; ++j) W[i][j] -= f * W[p][j];
        }
    }
    float Aloc[NS_][NO_];
    for (int s = 0; s < NS_; ++s) {
        for (int o = 0; o < NO_; ++o) {
            float acc = 0.f;
            for (int p = 0; p < NO_; ++p) acc += H[p * NS_ + s] * W[p][NO_ + o];
            Aloc[s][o] = acc;
            A[s * NO_ + o] = acc;
        }
    }
    for (int s = 0; s < NS_; ++s) {
        for (int q = 0; q < NS_; ++q) {
            float acc = 0.f;
            for (int o = 0; o < NO_; ++o) acc += Aloc[s][o] * H[o * NS_ + q];
            M[s * NS_ + q] = acc;
        }
    }
}

// ---------------------------------------------------------------------------
// Phase 1: GRU scan. One block per sample n; 192 threads = one gate row each.
// h lives in LDS; W_hh row (64f) + W_ih row (10f) cached in registers.
// Writes h_t for all t to workspace (N*T, 64) f32.
// ---------------------------------------------------------------------------
__global__ __launch_bounds__(G3_) void gru_kernel(
    const float* __restrict__ Y,     // (N,T,NO)
    const float* __restrict__ W_ih,  // (192,10)
    const float* __restrict__ W_hh,  // (192,64)
    const float* __restrict__ b_ih,
    const float* __restrict__ b_hh,
    float* __restrict__ h_out)       // (N*T,64)
{
    const int n = blockIdx.x;
    const int g = threadIdx.x;

    float wih[NO_];
#pragma unroll
    for (int i = 0; i < NO_; ++i) wih[i] = W_ih[g * NO_ + i];
    float whh[HID_];
#pragma unroll
    for (int k = 0; k < HID_; ++k) whh[k] = W_hh[g * HID_ + k];
    const float bi = b_ih[g];
    const float bh = b_hh[g];

    __shared__ float h_lds[HID_];
    __shared__ float xp_lds[G3_];
    __shared__ float hp_lds[G3_];
    if (g < HID_) h_lds[g] = 0.f;
    __syncthreads();

    const float* Yn = Y + (size_t)n * T_ * NO_;
    float* hout_n = h_out + (size_t)n * T_ * HID_;

    for (int t = 0; t < T_; ++t) {
        // input projection for this gate row (uniform Y across threads -> broadcast)
        const float* yt = Yn + t * NO_;
        float xv = bi;
#pragma unroll
        for (int i = 0; i < NO_; ++i) xv += wih[i] * yt[i];
        // hidden projection: 64-deep dot, 4 independent accumulators
        float a0 = 0.f, a1 = 0.f, a2 = 0.f, a3 = 0.f;
#pragma unroll
        for (int k = 0; k < HID_; k += 4) {
            a0 += whh[k + 0] * h_lds[k + 0];
            a1 += whh[k + 1] * h_lds[k + 1];
            a2 += whh[k + 2] * h_lds[k + 2];
            a3 += whh[k + 3] * h_lds[k + 3];
        }
        float hv = bh + ((a0 + a1) + (a2 + a3));
        xp_lds[g] = xv;
        hp_lds[g] = hv;
        __syncthreads();
        if (g < HID_) {
            float r = 1.f / (1.f + __expf(-(xp_lds[g] + hp_lds[g])));
            float z = 1.f / (1.f + __expf(-(xp_lds[HID_ + g] + hp_lds[HID_ + g])));
            float nx = xp_lds[2 * HID_ + g] + r * hp_lds[2 * HID_ + g];
            nx = fminf(fmaxf(nx, -15.f), 15.f);       // avoid inf/inf in tanh
            float e = __expf(2.f * nx);
            float nn = (e - 1.f) / (e + 1.f);         // tanh
            float h_new = (1.f - z) * nn + z * h_lds[g];
            h_lds[g] = h_new;
            hout_n[t * HID_ + g] = h_new;
        }
        __syncthreads();
    }
}

// ---------------------------------------------------------------------------
// Phase 2a: init output with the constant term 0.5*NS*T*log(2*pi)
// ---------------------------------------------------------------------------
__global__ void init_out(float* __restrict__ out)
{
    if (threadIdx.x == 0 && blockIdx.x == 0) {
        out[0] = 0.5f * (float)NS_ * (float)T_ * logf(2.f * 3.14159265358979323846f);
    }
}

// ---------------------------------------------------------------------------
// Phase 2b: per-(n,t) dense head + information-form Kalman + log-pdf terms.
// One lane per task. Woodbury: L_inv = M + diag(1/v); Cholesky gives logdet
// and mu_post; quad = ||L^T (x - mu_post)||^2. Reduce to one atomic per block.
// ---------------------------------------------------------------------------
__global__ __launch_bounds__(256) void post_kernel(
    const float* __restrict__ h_out,  // (N*T,64)
    const float* __restrict__ Y,      // (N,T,NO)
    const float* __restrict__ X,      // (N,T,NS)
    const float* __restrict__ W_fc, const float* __restrict__ b_fc,
    const float* __restrict__ W_mean, const float* __restrict__ b_mean,
    const float* __restrict__ W_vars, const float* __restrict__ b_vars,
    const float* __restrict__ Ac,     // (NS,NO)
    const float* __restrict__ Mc,     // (NS,NS)
    float* __restrict__ out)
{
    __shared__ float sWfc[DENSE_][HID_];
    __shared__ float sWm[NS_][DENSE_];
    __shared__ float sWv[NS_][DENSE_];
    __shared__ float sA[NS_][NO_];
    __shared__ float sM[NS_][NS_];
    __shared__ float sbfc[DENSE_], sbm[NS_], sbv[NS_];
    __shared__ float wsum[4];

    for (int i = threadIdx.x; i < DENSE_ * HID_; i += blockDim.x)
        sWfc[i / HID_][i % HID_] = W_fc[i];
    for (int i = threadIdx.x; i < NS_ * DENSE_; i += blockDim.x) {
        sWm[i / DENSE_][i % DENSE_] = W_mean[i];
        sWv[i / DENSE_][i % DENSE_] = W_vars[i];
    }
    for (int i = threadIdx.x; i < NS_ * NO_; i += blockDim.x) sA[i / NO_][i % NO_] = Ac[i];
    for (int i = threadIdx.x; i < NS_ * NS_; i += blockDim.x) sM[i / NS_][i % NS_] = Mc[i];
    if (threadIdx.x < DENSE_) sbfc[threadIdx.x] = b_fc[threadIdx.x];
    if (threadIdx.x < NS_) { sbm[threadIdx.x] = b_mean[threadIdx.x]; sbv[threadIdx.x] = b_vars[threadIdx.x]; }
    __syncthreads();

    const int task = blockIdx.x * blockDim.x + threadIdx.x;
    float contrib = 0.f;
    if (task < N_ * T_) {
        // ---- dense head: y = relu(W_fc h + b_fc) ----
        float y[DENSE_];
#pragma unroll
        for (int d = 0; d < DENSE_; ++d) y[d] = sbfc[d];
        const float* hp = h_out + (size_t)task * HID_;
#pragma unroll
        for (int k = 0; k < HID_; k += 4) {
            float4 h4 = *(const float4*)(hp + k);
#pragma unroll
            for (int d = 0; d < DENSE_; ++d) {
                y[d] += sWfc[d][k + 0] * h4.x + sWfc[d][k + 1] * h4.y +
                        sWfc[d][k + 2] * h4.z + sWfc[d][k + 3] * h4.w;
            }
        }
#pragma unroll
        for (int d = 0; d < DENSE_; ++d) y[d] = fmaxf(y[d], 0.f);

        // ---- mu_prev, vars_prev ----
        float mu[NS_], vinv[NS_];
#pragma unroll
        for (int s = 0; s < NS_; ++s) {
            float am = sbm[s], av = sbv[s];
#pragma unroll
            for (int d = 0; d < DENSE_; ++d) { am += sWm[s][d] * y[d]; av += sWv[s][d] * y[d]; }
            mu[s] = am;
            float sp = (av > 20.f) ? av : log1pf(__expf(av));  // softplus
            vinv[s] = 1.f / sp;
        }

        // ---- info-form posterior: b = v^-1 * mu + A * y_obs ----
        const float* yo = Y + (size_t)task * NO_;
        const float* xo = X + (size_t)task * NS_;
        float b[NS_];
#pragma unroll
        for (int s = 0; s < NS_; ++s) {
            float acc = vinv[s] * mu[s];
#pragma unroll
            for (int o = 0; o < NO_; ++o) acc += sA[s][o] * yo[o];
            b[s] = acc;
        }

        // ---- L_inv = M + diag(v^-1), Cholesky (lower, fully unrolled) ----
        float L[NS_][NS_];
#pragma unroll
        for (int i = 0; i < NS_; ++i)
#pragma unroll
            for (int j = 0; j <= i; ++j)
                L[i][j] = sM[i][j] + ((i == j) ? vinv[i] : 0.f);
        float ld = 0.f;
        float dinv[NS_];
#pragma unroll
        for (int j = 0; j < NS_; ++j) {
            float s = L[j][j];
#pragma unroll
            for (int k = 0; k < j; ++k) s -= L[j][k] * L[j][k];
            float d = sqrtf(s);
            ld += __logf(d);
            float di = 1.f / d;
            dinv[j] = di;
            L[j][j] = d;
#pragma unroll
            for (int i = j + 1; i < NS_; ++i) {
                float t2 = L[i][j];
#pragma unroll
                for (int k = 0; k < j; ++k) t2 -= L[i][k] * L[j][k];
                L[i][j] = t2 * di;
            }
        }
        ld *= 2.f;  // logdet(L_inv) = -logdet(L_post)

        // ---- solve L L^T mu_post = b ----
        float w[NS_];
#pragma unroll
        for (int i = 0; i < NS_; ++i) {
            float s = b[i];
#pragma unroll
            for (int k = 0; k < i; ++k) s -= L[i][k] * w[k];
            w[i] = s * dinv[i];
        }
        float mpost[NS_];
#pragma unroll
        for (int ii = NS_ - 1; ii >= 0; --ii) {
            float s = w[ii];
#pragma unroll
            for (int k = ii + 1; k < NS_; ++k) s -= L[k][ii] * mpost[k];
            mpost[ii] = s * dinv[ii];
        }

        // ---- quad = || L^T (x - mu_post) ||^2 ----
        float diff[NS_];
#pragma unroll
        for (int s = 0; s < NS_; ++s) diff[s] = xo[s] - mpost[s];
        float quad = 0.f;
#pragma unroll
        for (int j = 0; j < NS_; ++j) {
            float u = 0.f;
#pragma unroll
            for (int i = j; i < NS_; ++i) u += L[i][j] * diff[i];
            quad += u * u;
        }

        contrib = 0.5f * (ld - quad) * (1.0f / (float)N_);
    }

    // ---- block reduction -> one atomic ----
#pragma unroll
    for (int off = 32; off; off >>= 1) contrib += __shfl_down(contrib, off);
    const int wid = threadIdx.x >> 6;
    if ((threadIdx.x & 63) == 0) wsum[wid] = contrib;
    __syncthreads();
    if (threadIdx.x == 0) {
        float s = 0.f;
#pragma unroll
        for (int i = 0; i < 4; ++i) s += wsum[i];
        atomicAdd(out, s);
    }
}

// ---------------------------------------------------------------------------
extern "C" void kernel_launch(void* const* d_in, const int* in_sizes, int n_in,
                              void* d_out, int out_size, void* d_ws, size_t ws_size,
                              hipStream_t stream)
{
    const float* Y      = (const float*)d_in[0];
    const float* X      = (const float*)d_in[1];
    const float* H      = (const float*)d_in[2];
    // d_in[3] = mu_w (unused by reference)
    const float* C_w    = (const float*)d_in[4];
    const float* W_ih   = (const float*)d_in[5];
    const float* W_hh   = (const float*)d_in[6];
    const float* b_ih   = (const float*)d_in[7];
    const float* b_hh   = (const float*)d_in[8];
    const float* W_fc   = (const float*)d_in[9];
    const float* b_fc   = (const float*)d_in[10];
    const float* W_mean = (const float*)d_in[11];
    const float* b_mean = (const float*)d_in[12];
    const float* W_vars = (const float*)d_in[13];
    const float* b_vars = (const float*)d_in[14];
    float* out = (float*)d_out;

    // workspace: h_out (N*T*64 f32 = 32.77 MB) + constants A (100) + M (100)
    float* h_out = (float*)d_ws;
    float* Ac = h_out + (size_t)N_ * T_ * HID_;
    float* Mc = Ac + NS_ * NO_;

    hipLaunchKernelGGL(setup_consts, dim3(1), dim3(64), 0, stream, H, C_w, Ac, Mc);
    hipLaunchKernelGGL(gru_kernel, dim3(N_), dim3(G3_), 0, stream,
                       Y, W_ih, W_hh, b_ih, b_hh, h_out);
    hipLaunchKernelGGL(init_out, dim3(1), dim3(1), 0, stream, out);
    hipLaunchKernelGGL(post_kernel, dim3((N_ * T_ + 255) / 256), dim3(256), 0, stream,
                       h_out, Y, X, W_fc, b_fc, W_mean, b_mean, W_vars, b_vars,
                       Ac, Mc, out);
}

// Round 2
// 773.735 us; speedup vs baseline: 1.3535x; 1.3535x over previous
//
#include <hip/hip_runtime.h>
#include <math.h>

// Problem constants (from reference)
#define N_    128
#define T_    1000
#define NS_   10
#define NO_   10
#define HID_  64
#define G3_   192   // 3*HID
#define DENSE_ 32

// Barrier that waits only on LDS ops (no vmcnt drain: global stores in the
// scan are consumed by a later dispatch, never by another wave in-kernel).
#define LDS_BARRIER() asm volatile("s_waitcnt lgkmcnt(0)\n\ts_barrier" ::: "memory")

__device__ __forceinline__ float fast_sigmoid(float x) {
    // 1/(1+e^-x); e^-x=inf -> rcp(inf)=0 -> 0  (NaN-safe, no clamp needed)
    return __builtin_amdgcn_rcpf(1.f + __expf(-x));
}
__device__ __forceinline__ float fast_tanh(float x) {
    // 1 - 2/(e^{2x}+1); e=inf -> 1; e=0 -> -1  (NaN-safe)
    float e = __expf(2.f * x);
    return 1.f - 2.f * __builtin_amdgcn_rcpf(e + 1.f);
}

// ---------------------------------------------------------------------------
// Phase 0: precompute A = H^T inv(C_w) (NS x NO), M = A H (NS x NS)
// ---------------------------------------------------------------------------
__global__ void setup_consts(const float* __restrict__ H,
                             const float* __restrict__ C_w,
                             float* __restrict__ A,   // (NS,NO)
                             float* __restrict__ M)   // (NS,NS)
{
    if (threadIdx.x != 0 || blockIdx.x != 0) return;
    float W[NO_][2 * NO_];
    for (int i = 0; i < NO_; ++i) {
        for (int j = 0; j < NO_; ++j) {
            W[i][j] = C_w[i * NO_ + j];
            W[i][NO_ + j] = (i == j) ? 1.f : 0.f;
        }
    }
    for (int p = 0; p < NO_; ++p) {
        float ip = 1.f / W[p][p];
        for (int j = 0; j < 2 * NO_; ++j) W[p][j] *= ip;
        for (int i = 0; i < NO_; ++i) {
            if (i == p) continue;
            float f = W[i][p];
            for (int j = 0; j < 2 * NO_; ++j) W[i][j] -= f * W[p][j];
        }
    }
    float Aloc[NS_][NO_];
    for (int s = 0; s < NS_; ++s) {
        for (int o = 0; o < NO_; ++o) {
            float acc = 0.f;
            for (int p = 0; p < NO_; ++p) acc += H[p * NS_ + s] * W[p][NO_ + o];
            Aloc[s][o] = acc;
            A[s * NO_ + o] = acc;
        }
    }
    for (int s = 0; s < NS_; ++s) {
        for (int q = 0; q < NS_; ++q) {
            float acc = 0.f;
            for (int o = 0; o < NO_; ++o) acc += Aloc[s][o] * H[o * NS_ + q];
            M[s * NS_ + q] = acc;
        }
    }
}

// ---------------------------------------------------------------------------
// Phase 1: GRU scan. One block per sample; 3 waves = gates r/z/n, one gate
// row per lane. Structure per step:
//   - xv from register-prefetched y (loads for t+1 issued here, used next it.)
//   - 64-deep hidden dot via float4 broadcast reads of h_lds
//   - each gate wave applies its OWN nonlinearity in parallel (r stays in reg
//     on wave 0, which is also the update wave); z / xn / hn go through LDS
//   - LDS-only barrier (no vmcnt drain)
//   - wave 0: tanh chain + h update + h_lds write + fire-and-forget h_out store
//   - LDS-only barrier
// ---------------------------------------------------------------------------
__global__ __launch_bounds__(G3_) void gru_kernel(
    const float* __restrict__ Y,     // (N,T,NO)
    const float* __restrict__ W_ih,  // (192,10)
    const float* __restrict__ W_hh,  // (192,64)
    const float* __restrict__ b_ih,
    const float* __restrict__ b_hh,
    float* __restrict__ h_out)       // (N*T,64)
{
    const int n = blockIdx.x;
    const int g = threadIdx.x;       // 0..191
    const int gate = g >> 6;         // 0=r, 1=z, 2=n (uniform per wave)
    const int j = g & 63;

    float wih[NO_];
#pragma unroll
    for (int i = 0; i < NO_; ++i) wih[i] = W_ih[g * NO_ + i];
    float whh[HID_];
#pragma unroll
    for (int k = 0; k < HID_; ++k) whh[k] = W_hh[g * HID_ + k];
    const float bi = b_ih[g];
    const float bh = b_hh[g];

    __shared__ __align__(16) float h_lds[HID_];
    __shared__ float z_lds[HID_];
    __shared__ float xn_lds[HID_];
    __shared__ float hn_lds[HID_];

    if (g < HID_) h_lds[g] = 0.f;
    float h_own = 0.f;               // wave-0 register copy of h[j]
    LDS_BARRIER();

    const float* Yn = Y + (size_t)n * T_ * NO_;
    float* hout_n = h_out + (size_t)n * T_ * HID_;

    // prefetch y[0] (rows are 40B -> 8B aligned; use float2 x5)
    float y[NO_];
    {
        const float2* yp = (const float2*)Yn;
#pragma unroll
        for (int i = 0; i < NO_ / 2; ++i) {
            float2 v = yp[i];
            y[2 * i] = v.x; y[2 * i + 1] = v.y;
        }
    }

    for (int t = 0; t < T_; ++t) {
        // input projection from registers
        float xv = bi;
#pragma unroll
        for (int i = 0; i < NO_; ++i) xv += wih[i] * y[i];

        // prefetch y[t+1] (clamped; loads overlap the hidden dot below)
        {
            const int tn = (t + 1 < T_) ? t + 1 : t;
            const float2* yp = (const float2*)(Yn + tn * NO_);
#pragma unroll
            for (int i = 0; i < NO_ / 2; ++i) {
                float2 v = yp[i];
                y[2 * i] = v.x; y[2 * i + 1] = v.y;
            }
        }

        // hidden projection: broadcast float4 reads, 4 accumulators
        float a0 = 0.f, a1 = 0.f, a2 = 0.f, a3 = 0.f;
        const float4* h4p = (const float4*)h_lds;
#pragma unroll
        for (int k = 0; k < HID_ / 4; ++k) {
            float4 h4 = h4p[k];
            a0 += whh[4 * k + 0] * h4.x;
            a1 += whh[4 * k + 1] * h4.y;
            a2 += whh[4 * k + 2] * h4.z;
            a3 += whh[4 * k + 3] * h4.w;
        }
        const float pre = xv + (bh + ((a0 + a1) + (a2 + a3)));

        // per-gate nonlinearity, in parallel across the 3 waves
        float r_own = 0.f;
        if (gate == 0) {
            r_own = fast_sigmoid(pre);           // stays in register (update wave)
        } else if (gate == 1) {
            z_lds[j] = fast_sigmoid(pre);
        } else {
            xn_lds[j] = xv;                      // n-gate needs r before combining
            hn_lds[j] = pre - xv;                // = hv + bh portion
        }
        LDS_BARRIER();

        if (gate == 0) {
            const float z  = z_lds[j];
            const float nn = fast_tanh(xn_lds[j] + r_own * hn_lds[j]);
            const float h_new = (1.f - z) * nn + z * h_own;
            h_own = h_new;
            h_lds[j] = h_new;
            hout_n[t * HID_ + j] = h_new;        // fire-and-forget (no drain)
        }
        LDS_BARRIER();
    }
}

// ---------------------------------------------------------------------------
// Phase 2a: init output with the constant term 0.5*NS*T*log(2*pi)
// ---------------------------------------------------------------------------
__global__ void init_out(float* __restrict__ out)
{
    if (threadIdx.x == 0 && blockIdx.x == 0) {
        out[0] = 0.5f * (float)NS_ * (float)T_ * logf(2.f * 3.14159265358979323846f);
    }
}

// ---------------------------------------------------------------------------
// Phase 2b: per-(n,t) dense head + information-form Kalman + log-pdf terms.
// ---------------------------------------------------------------------------
__global__ __launch_bounds__(256) void post_kernel(
    const float* __restrict__ h_out,  // (N*T,64)
    const float* __restrict__ Y,      // (N,T,NO)
    const float* __restrict__ X,      // (N,T,NS)
    const float* __restrict__ W_fc, const float* __restrict__ b_fc,
    const float* __restrict__ W_mean, const float* __restrict__ b_mean,
    const float* __restrict__ W_vars, const float* __restrict__ b_vars,
    const float* __restrict__ Ac,     // (NS,NO)
    const float* __restrict__ Mc,     // (NS,NS)
    float* __restrict__ out)
{
    __shared__ float sWfc[DENSE_][HID_];
    __shared__ float sWm[NS_][DENSE_];
    __shared__ float sWv[NS_][DENSE_];
    __shared__ float sA[NS_][NO_];
    __shared__ float sM[NS_][NS_];
    __shared__ float sbfc[DENSE_], sbm[NS_], sbv[NS_];
    __shared__ float wsum[4];

    for (int i = threadIdx.x; i < DENSE_ * HID_; i += blockDim.x)
        sWfc[i / HID_][i % HID_] = W_fc[i];
    for (int i = threadIdx.x; i < NS_ * DENSE_; i += blockDim.x) {
        sWm[i / DENSE_][i % DENSE_] = W_mean[i];
        sWv[i / DENSE_][i % DENSE_] = W_vars[i];
    }
    for (int i = threadIdx.x; i < NS_ * NO_; i += blockDim.x) sA[i / NO_][i % NO_] = Ac[i];
    for (int i = threadIdx.x; i < NS_ * NS_; i += blockDim.x) sM[i / NS_][i % NS_] = Mc[i];
    if (threadIdx.x < DENSE_) sbfc[threadIdx.x] = b_fc[threadIdx.x];
    if (threadIdx.x < NS_) { sbm[threadIdx.x] = b_mean[threadIdx.x]; sbv[threadIdx.x] = b_vars[threadIdx.x]; }
    __syncthreads();

    const int task = blockIdx.x * blockDim.x + threadIdx.x;
    float contrib = 0.f;
    if (task < N_ * T_) {
        float y[DENSE_];
#pragma unroll
        for (int d = 0; d < DENSE_; ++d) y[d] = sbfc[d];
        const float* hp = h_out + (size_t)task * HID_;
#pragma unroll
        for (int k = 0; k < HID_; k += 4) {
            float4 h4 = *(const float4*)(hp + k);
#pragma unroll
            for (int d = 0; d < DENSE_; ++d) {
                y[d] += sWfc[d][k + 0] * h4.x + sWfc[d][k + 1] * h4.y +
                        sWfc[d][k + 2] * h4.z + sWfc[d][k + 3] * h4.w;
            }
        }
#pragma unroll
        for (int d = 0; d < DENSE_; ++d) y[d] = fmaxf(y[d], 0.f);

        float mu[NS_], vinv[NS_];
#pragma unroll
        for (int s = 0; s < NS_; ++s) {
            float am = sbm[s], av = sbv[s];
#pragma unroll
            for (int d = 0; d < DENSE_; ++d) { am += sWm[s][d] * y[d]; av += sWv[s][d] * y[d]; }
            mu[s] = am;
            float sp = (av > 20.f) ? av : log1pf(__expf(av));  // softplus
            vinv[s] = 1.f / sp;
        }

        const float* yo = Y + (size_t)task * NO_;
        const float* xo = X + (size_t)task * NS_;
        float b[NS_];
#pragma unroll
        for (int s = 0; s < NS_; ++s) {
            float acc = vinv[s] * mu[s];
#pragma unroll
            for (int o = 0; o < NO_; ++o) acc += sA[s][o] * yo[o];
            b[s] = acc;
        }

        // L_inv = M + diag(v^-1), Cholesky
        float L[NS_][NS_];
#pragma unroll
        for (int i = 0; i < NS_; ++i)
#pragma unroll
            for (int j = 0; j <= i; ++j)
                L[i][j] = sM[i][j] + ((i == j) ? vinv[i] : 0.f);
        float ld = 0.f;
        float dinv[NS_];
#pragma unroll
        for (int j = 0; j < NS_; ++j) {
            float s = L[j][j];
#pragma unroll
            for (int k = 0; k < j; ++k) s -= L[j][k] * L[j][k];
            float d = sqrtf(s);
            ld += __logf(d);
            float di = 1.f / d;
            dinv[j] = di;
            L[j][j] = d;
#pragma unroll
            for (int i = j + 1; i < NS_; ++i) {
                float t2 = L[i][j];
#pragma unroll
                for (int k = 0; k < j; ++k) t2 -= L[i][k] * L[j][k];
                L[i][j] = t2 * di;
            }
        }
        ld *= 2.f;

        float w[NS_];
#pragma unroll
        for (int i = 0; i < NS_; ++i) {
            float s = b[i];
#pragma unroll
            for (int k = 0; k < i; ++k) s -= L[i][k] * w[k];
            w[i] = s * dinv[i];
        }
        float mpost[NS_];
#pragma unroll
        for (int ii = NS_ - 1; ii >= 0; --ii) {
            float s = w[ii];
#pragma unroll
            for (int k = ii + 1; k < NS_; ++k) s -= L[k][ii] * mpost[k];
            mpost[ii] = s * dinv[ii];
        }

        float diff[NS_];
#pragma unroll
        for (int s = 0; s < NS_; ++s) diff[s] = xo[s] - mpost[s];
        float quad = 0.f;
#pragma unroll
        for (int j = 0; j < NS_; ++j) {
            float u = 0.f;
#pragma unroll
            for (int i = j; i < NS_; ++i) u += L[i][j] * diff[i];
            quad += u * u;
        }

        contrib = 0.5f * (ld - quad) * (1.0f / (float)N_);
    }

#pragma unroll
    for (int off = 32; off; off >>= 1) contrib += __shfl_down(contrib, off);
    const int wid = threadIdx.x >> 6;
    if ((threadIdx.x & 63) == 0) wsum[wid] = contrib;
    __syncthreads();
    if (threadIdx.x == 0) {
        float s = 0.f;
#pragma unroll
        for (int i = 0; i < 4; ++i) s += wsum[i];
        atomicAdd(out, s);
    }
}

// ---------------------------------------------------------------------------
extern "C" void kernel_launch(void* const* d_in, const int* in_sizes, int n_in,
                              void* d_out, int out_size, void* d_ws, size_t ws_size,
                              hipStream_t stream)
{
    const float* Y      = (const float*)d_in[0];
    const float* X      = (const float*)d_in[1];
    const float* H      = (const float*)d_in[2];
    const float* C_w    = (const float*)d_in[4];
    const float* W_ih   = (const float*)d_in[5];
    const float* W_hh   = (const float*)d_in[6];
    const float* b_ih   = (const float*)d_in[7];
    const float* b_hh   = (const float*)d_in[8];
    const float* W_fc   = (const float*)d_in[9];
    const float* b_fc   = (const float*)d_in[10];
    const float* W_mean = (const float*)d_in[11];
    const float* b_mean = (const float*)d_in[12];
    const float* W_vars = (const float*)d_in[13];
    const float* b_vars = (const float*)d_in[14];
    float* out = (float*)d_out;

    float* h_out = (float*)d_ws;                       // 32.77 MB
    float* Ac = h_out + (size_t)N_ * T_ * HID_;
    float* Mc = Ac + NS_ * NO_;

    hipLaunchKernelGGL(setup_consts, dim3(1), dim3(64), 0, stream, H, C_w, Ac, Mc);
    hipLaunchKernelGGL(gru_kernel, dim3(N_), dim3(G3_), 0, stream,
                       Y, W_ih, W_hh, b_ih, b_hh, h_out);
    hipLaunchKernelGGL(init_out, dim3(1), dim3(1), 0, stream, out);
    hipLaunchKernelGGL(post_kernel, dim3((N_ * T_ + 255) / 256), dim3(256), 0, stream,
                       h_out, Y, X, W_fc, b_fc, W_mean, b_mean, W_vars, b_vars,
                       Ac, Mc, out);
}